// Round 1
// baseline (835.734 us; speedup 1.0000x reference)
//
#include <hip/hip_runtime.h>
#include <hip/hip_bf16.h>
#include <math.h>

#define NCLS 80
#define TOPK_N 1000
#define CAND_CAP 8192
#define HIST_BINS 131072   // 17-bit bins of float score bits

// ---- workspace layout (bytes), M = 300000 ----
#define WS_SCORES   0          // 300000 f32
#define WS_LABELS   1200000    // 300000 i32
#define WS_HIST     2400000    // 131072 u32
#define WS_META     2924288    // [0]=bin B, [1]=count_above, [2]=cand counter
#define WS_CAND     2924352    // 8192 u64
#define WS_TKSCORE  2989888    // 1000 f32
#define WS_TKLABEL  2993888    // 1000 i32
#define WS_BOXES    2997888    // 1000 float4 (original boxes)
#define WS_OBX      3013888    // 1000 float4 (class-offset boxes)
#define WS_AREAS    3029888    // 1000 f32
#define WS_MASK     3033888    // 1000 * 16 u64 suppression bitmask
#define WS_KEEPF    3161888    // 1000 f32
// total ~3.02 MB

typedef unsigned long long u64;

__device__ __forceinline__ float sigmoidf_(float x) {
    return 1.0f / (1.0f + expf(-x));
}

// K1: one wave per anchor: row max+argmax over 80 classes, fused score, histogram.
__global__ void k1_scores(const float* __restrict__ obj,
                          const float* __restrict__ cls,
                          float* __restrict__ scores,
                          int* __restrict__ labels,
                          unsigned* __restrict__ hist, int M) {
    int wave = (blockIdx.x * blockDim.x + threadIdx.x) >> 6;
    int lane = threadIdx.x & 63;
    if (wave >= M) return;
    const float* row = cls + (size_t)wave * NCLS;
    float v = row[lane];
    int c = lane;
    if (lane < NCLS - 64) {
        float v2 = row[64 + lane];
        if (v2 > v) { v = v2; c = 64 + lane; }   // strict > keeps first-max
    }
    for (int off = 32; off > 0; off >>= 1) {
        float ov = __shfl_down(v, off);
        int oc = __shfl_down(c, off);
        if (ov > v || (ov == v && oc < c)) { v = ov; c = oc; }
    }
    if (lane == 0) {
        float so = sigmoidf_(obj[wave]);
        float sc = sigmoidf_(v);
        float score = sqrtf(so * sc);
        scores[wave] = score;
        labels[wave] = c;
        unsigned key = __float_as_uint(score);   // positive -> monotone bits
        atomicAdd(&hist[key >> 15], 1u);
    }
}

// K2: find threshold bin B (descending) where cumulative count reaches TOPK_N.
__global__ void k2_scan(const unsigned* __restrict__ hist, int* __restrict__ meta) {
    int t = threadIdx.x;              // 1024
    int lane = t & 63, w = t >> 6;    // 16 waves
    int base = HIST_BINS - 1 - t * 128;
    unsigned s = 0;
    for (int k = 0; k < 128; ++k) s += hist[base - k];
    unsigned inc = s;
    for (int d = 1; d < 64; d <<= 1) {
        unsigned pv = __shfl_up(inc, d);
        if (lane >= d) inc += pv;
    }
    __shared__ unsigned wsum[16], woff[16];
    if (lane == 63) wsum[w] = inc;
    __syncthreads();
    if (t == 0) {
        unsigned cum = 0;
        for (int i = 0; i < 16; ++i) { woff[i] = cum; cum += wsum[i]; }
    }
    __syncthreads();
    unsigned excl = woff[w] + inc - s;
    if (excl < TOPK_N && excl + s >= TOPK_N) {   // exactly one thread
        unsigned cum = excl; int b = base;
        for (int k = 0; k < 128; ++k) {
            unsigned h = hist[b];
            if (cum + h >= TOPK_N) { meta[0] = b; meta[1] = (int)cum; break; }
            cum += h; --b;
        }
    }
}

// K3: compact candidates with key_high >= B into composite keys.
__global__ void k3_compact(const float* __restrict__ scores,
                           const int* __restrict__ meta,
                           u64* __restrict__ cand,
                           int* __restrict__ counter, int M) {
    int i = blockIdx.x * blockDim.x + threadIdx.x;
    if (i >= M) return;
    unsigned key = __float_as_uint(scores[i]);
    if ((int)(key >> 15) >= meta[0]) {
        int pos = atomicAdd(counter, 1);
        if (pos < CAND_CAP) {
            cand[pos] = ((u64)key << 32) | (unsigned)(~i);
        }
    }
}

// K4: single-block bitonic sort (descending via inverted keys), gather top-1000.
__global__ void k4_sort(const u64* __restrict__ cand,
                        const int* __restrict__ meta,
                        const int* __restrict__ labels,
                        const float4* __restrict__ box,
                        float* __restrict__ tkscore,
                        int* __restrict__ tklabel,
                        float4* __restrict__ boxes_k,
                        float4* __restrict__ obx,
                        float* __restrict__ areas) {
    __shared__ u64 s[CAND_CAP];
    int t = threadIdx.x;              // 1024
    int C = meta[2];
    if (C > CAND_CAP) C = CAND_CAP;
    int P = 1024;
    while (P < C) P <<= 1;
    for (int j = t; j < P; j += 1024) s[j] = (j < C) ? ~cand[j] : ~0ULL;
    __syncthreads();
    for (int kk = 2; kk <= P; kk <<= 1) {
        for (int j = kk >> 1; j > 0; j >>= 1) {
            for (int tid = t; tid < P; tid += 1024) {
                int ixj = tid ^ j;
                if (ixj > tid) {
                    u64 a = s[tid], b = s[ixj];
                    bool asc = ((tid & kk) == 0);
                    bool sw = asc ? (a > b) : (a < b);
                    if (sw) { s[tid] = b; s[ixj] = a; }
                }
            }
            __syncthreads();
        }
    }
    if (t < TOPK_N) {
        u64 comp = ~s[t];
        unsigned key = (unsigned)(comp >> 32);
        int anchor = (int)(~(unsigned)comp);
        float sc = __uint_as_float(key);
        tkscore[t] = sc;
        int lab = labels[anchor];
        tklabel[t] = lab;
        float4 b = box[anchor];
        boxes_k[t] = b;
        float off = (float)lab * 4096.0f;
        float4 ob = make_float4(b.x + off, b.y + off, b.z + off, b.w + off);
        obx[t] = ob;
        areas[t] = fmaxf(ob.z - ob.x, 0.0f) * fmaxf(ob.w - ob.y, 0.0f);
    }
}

// K5: 1000x1000 suppression bitmask: bit j of row i set iff j>i and IoU>0.5.
__global__ void k5_iou(const float4* __restrict__ obx,
                       const float* __restrict__ areas,
                       u64* __restrict__ mask) {
    int i = blockIdx.x;
    int lane = threadIdx.x;           // 64
    float4 bi = obx[i];
    float ai = areas[i];
    for (int w = 0; w < 16; ++w) {
        int c = w * 64 + lane;
        bool bit = false;
        if (c < TOPK_N && c > i) {
            float4 bc = obx[c];
            float xx1 = fmaxf(bi.x, bc.x), yy1 = fmaxf(bi.y, bc.y);
            float xx2 = fminf(bi.z, bc.z), yy2 = fminf(bi.w, bc.w);
            float inter = fmaxf(xx2 - xx1, 0.0f) * fmaxf(yy2 - yy1, 0.0f);
            float iou = inter / (ai + areas[c] - inter + 1e-9f);
            bit = iou > 0.5f;
        }
        u64 bal = __ballot(bit);
        if (lane == 0) mask[(size_t)i * 16 + w] = bal;
    }
}

// K6: sequential greedy scan, single wave, removed bitmask in lanes 0..15.
__global__ void k6_nms(const float* __restrict__ tkscore,
                       const u64* __restrict__ mask,
                       float* __restrict__ keepf) {
    int lane = threadIdx.x;           // 64
    u64 removed = 0ULL;
    for (int i = 0; i < TOPK_N; ++i) {
        float sc = tkscore[i];
        u64 row = (lane < 16) ? mask[(size_t)i * 16 + lane] : 0ULL;
        int w = i >> 6, b = i & 63;
        int hi = __shfl((int)(removed >> 32), w);
        int lo = __shfl((int)(removed & 0xffffffffULL), w);
        u64 rw = ((u64)(unsigned)hi << 32) | (unsigned)lo;
        bool kept = (sc > 0.001f) && !((rw >> b) & 1ULL);
        if (kept) removed |= row;
        if (lane == 0) keepf[i] = kept ? 1.0f : 0.0f;
    }
}

// K7: final outputs: [1000x5 out5][1000 labels][1000 keep], all float32.
__global__ void k7_write(const float* __restrict__ tkscore,
                         const int* __restrict__ tklabel,
                         const float4* __restrict__ boxes_k,
                         const float* __restrict__ keepf,
                         float* __restrict__ out) {
    int j = blockIdx.x * blockDim.x + threadIdx.x;
    if (j >= TOPK_N) return;
    float k = keepf[j];
    float4 b = boxes_k[j];
    out[j * 5 + 0] = tkscore[j] * k;
    out[j * 5 + 1] = b.x * k;
    out[j * 5 + 2] = b.y * k;
    out[j * 5 + 3] = b.z * k;
    out[j * 5 + 4] = b.w * k;
    out[5 * TOPK_N + j] = (float)tklabel[j];
    out[6 * TOPK_N + j] = k;
}

extern "C" void kernel_launch(void* const* d_in, const int* in_sizes, int n_in,
                              void* d_out, int out_size, void* d_ws, size_t ws_size,
                              hipStream_t stream) {
    const float* obj = (const float*)d_in[0];
    const float* cls = (const float*)d_in[1];
    const float* box = (const float*)d_in[2];
    float* out = (float*)d_out;
    char* ws = (char*)d_ws;
    int M = in_sizes[0];   // 300000

    float*    scores  = (float*)(ws + WS_SCORES);
    int*      labels  = (int*)(ws + WS_LABELS);
    unsigned* hist    = (unsigned*)(ws + WS_HIST);
    int*      meta    = (int*)(ws + WS_META);
    u64*      cand    = (u64*)(ws + WS_CAND);
    float*    tkscore = (float*)(ws + WS_TKSCORE);
    int*      tklabel = (int*)(ws + WS_TKLABEL);
    float4*   boxes_k = (float4*)(ws + WS_BOXES);
    float4*   obx     = (float4*)(ws + WS_OBX);
    float*    areas   = (float*)(ws + WS_AREAS);
    u64*      mask    = (u64*)(ws + WS_MASK);
    float*    keepf   = (float*)(ws + WS_KEEPF);

    // zero histogram + meta (ws is poisoned 0xAA before every launch)
    hipMemsetAsync(ws + WS_HIST, 0, (size_t)HIST_BINS * 4 + 64, stream);

    int waves_per_block = 4;  // 256 threads
    int blocks1 = (M + waves_per_block - 1) / waves_per_block;
    k1_scores<<<blocks1, 256, 0, stream>>>(obj, cls, scores, labels, hist, M);
    k2_scan<<<1, 1024, 0, stream>>>(hist, meta);
    k3_compact<<<(M + 255) / 256, 256, 0, stream>>>(scores, meta, cand, meta + 2, M);
    k4_sort<<<1, 1024, 0, stream>>>(cand, meta, labels, (const float4*)box,
                                    tkscore, tklabel, boxes_k, obx, areas);
    k5_iou<<<TOPK_N, 64, 0, stream>>>(obx, areas, mask);
    k6_nms<<<1, 64, 0, stream>>>(tkscore, mask, keepf);
    k7_write<<<(TOPK_N + 63) / 64, 64, 0, stream>>>(tkscore, tklabel, boxes_k, keepf, out);
}

// Round 2
// 318.236 us; speedup vs baseline: 2.6261x; 2.6261x over previous
//
#include <hip/hip_runtime.h>
#include <hip/hip_bf16.h>
#include <math.h>

#define NCLS 80
#define TOPK_N 1000
#define CAND_CAP 4096
#define HIST_BINS 131072        // 17-bit bins of float score bits
#define REPLICA_BYTES (HIST_BINS * 4)

// ---- workspace layout (bytes), M = 300000 ----
#define WS_SCORES   0           // 300000 f32
#define WS_LABELS   1200000     // 300000 i32
#define WS_META     2400000     // [0]=bin B, [1]=count_above, [2]=cand counter
#define WS_CAND     2400064     // 4096 u64
#define WS_TKSCORE  2432832     // 1000 f32
#define WS_TKLABEL  2436832     // 1000 i32
#define WS_BOXES    2440832     // 1000 float4 (original boxes)
#define WS_OBX      2456832     // 1000 float4 (class-offset boxes)
#define WS_AREAS    2472832     // 1000 f32
#define WS_MASK     2476832     // 1000 * 16 u64 suppression bitmask
#define WS_KEEPF    2604832     // 1000 f32
#define WS_HIST     2608896     // R * 131072 u32 (replicated histogram)
// fixed + 1 replica = 3,133,184 B  (fits the proven >=3.16 MB ws)

typedef unsigned long long u64;

__device__ __forceinline__ float sigmoidf_(float x) {
    return 1.0f / (1.0f + expf(-x));
}

__device__ __forceinline__ u64 shfl64(u64 v, int src) {
    int hi = __shfl((int)(v >> 32), src);
    int lo = __shfl((int)(v & 0xffffffffULL), src);
    return ((u64)(unsigned)hi << 32) | (unsigned)lo;
}

__device__ __forceinline__ u64 shflxor64(u64 v, int m) {
    int hi = __shfl_xor((int)(v >> 32), m);
    int lo = __shfl_xor((int)(v & 0xffffffffULL), m);
    return ((u64)(unsigned)hi << 32) | (unsigned)lo;
}

// K1: 16 lanes per anchor (4 anchors/wave). float4 loads, shfl_xor reduce,
// replicated-histogram atomic (replica = blockIdx & (R-1)).
__global__ void k1_scores(const float* __restrict__ obj,
                          const float* __restrict__ cls,
                          float* __restrict__ scores,
                          int* __restrict__ labels,
                          unsigned* __restrict__ hist, int Rm1, int M) {
    int wave = (blockIdx.x * 256 + threadIdx.x) >> 6;
    int lane = threadIdx.x & 63;
    int g = lane >> 4, l = lane & 15;
    int anchor = wave * 4 + g;
    if (anchor >= M) return;
    const float4* row = (const float4*)(cls + (size_t)anchor * NCLS);
    float4 v4 = row[l];
    float bv = v4.x; int bc = l * 4;
    if (v4.y > bv) { bv = v4.y; bc = l * 4 + 1; }
    if (v4.z > bv) { bv = v4.z; bc = l * 4 + 2; }
    if (v4.w > bv) { bv = v4.w; bc = l * 4 + 3; }
    if (l < 4) {                         // classes 64..79
        float4 w4 = row[16 + l];
        int cb = 64 + l * 4;
        if (w4.x > bv) { bv = w4.x; bc = cb; }
        if (w4.y > bv) { bv = w4.y; bc = cb + 1; }
        if (w4.z > bv) { bv = w4.z; bc = cb + 2; }
        if (w4.w > bv) { bv = w4.w; bc = cb + 3; }
    }
    #pragma unroll
    for (int m = 8; m >= 1; m >>= 1) {   // reduce within 16-lane group
        float ov = __shfl_xor(bv, m);
        int oc = __shfl_xor(bc, m);
        if (ov > bv || (ov == bv && oc < bc)) { bv = ov; bc = oc; }
    }
    if (l == 0) {
        float so = sigmoidf_(obj[anchor]);
        float score = sqrtf(so * sigmoidf_(bv));
        scores[anchor] = score;
        labels[anchor] = bc;
        unsigned key = __float_as_uint(score);
        int rep = blockIdx.x & Rm1;
        atomicAdd(&hist[(size_t)rep * HIST_BINS + (key >> 15)], 1u);
    }
}

// K1b: fold R replicas into replica 0.
__global__ void k_hreduce(unsigned* __restrict__ hist, int R) {
    int b = blockIdx.x * 256 + threadIdx.x;
    unsigned s = hist[b];
    for (int r = 1; r < R; ++r) s += hist[(size_t)r * HIST_BINS + b];
    hist[b] = s;
}

// K2: find threshold bin B (descending) where cumulative count reaches TOPK_N.
__global__ void k2_scan(const unsigned* __restrict__ hist, int* __restrict__ meta) {
    int t = threadIdx.x;              // 1024
    int lane = t & 63, w = t >> 6;    // 16 waves
    int base = HIST_BINS - 1 - t * 128;
    unsigned s = 0;
    for (int k = 0; k < 128; ++k) s += hist[base - k];
    unsigned inc = s;
    for (int d = 1; d < 64; d <<= 1) {
        unsigned pv = __shfl_up(inc, d);
        if (lane >= d) inc += pv;
    }
    __shared__ unsigned wsum[16], woff[16];
    if (lane == 63) wsum[w] = inc;
    __syncthreads();
    if (t == 0) {
        unsigned cum = 0;
        for (int i = 0; i < 16; ++i) { woff[i] = cum; cum += wsum[i]; }
    }
    __syncthreads();
    unsigned excl = woff[w] + inc - s;
    if (excl < TOPK_N && excl + s >= TOPK_N) {   // exactly one thread
        unsigned cum = excl; int b = base;
        for (int k = 0; k < 128; ++k) {
            unsigned h = hist[b];
            if (cum + h >= TOPK_N) { meta[0] = b; meta[1] = (int)cum; break; }
            cum += h; --b;
        }
    }
}

// K3: compact candidates with key_high >= B into composite keys.
__global__ void k3_compact(const float* __restrict__ scores,
                           const int* __restrict__ meta,
                           u64* __restrict__ cand,
                           int* __restrict__ counter, int M) {
    int i = blockIdx.x * blockDim.x + threadIdx.x;
    if (i >= M) return;
    unsigned key = __float_as_uint(scores[i]);
    if ((int)(key >> 15) >= meta[0]) {
        int pos = atomicAdd(counter, 1);
        if (pos < CAND_CAP) {
            cand[pos] = ((u64)key << 32) | (unsigned)(~i);
        }
    }
}

// K4: rank-by-counting. rank(i) = #{j: key_j > key_i}; scatter rank < 1000.
__global__ void k4_rank(const u64* __restrict__ cand,
                        const int* __restrict__ meta,
                        const int* __restrict__ labels,
                        const float4* __restrict__ box,
                        float* __restrict__ tkscore,
                        int* __restrict__ tklabel,
                        float4* __restrict__ boxes_k,
                        float4* __restrict__ obx,
                        float* __restrict__ areas) {
    __shared__ u64 sk[CAND_CAP];
    int C = meta[2];
    if (C > CAND_CAP) C = CAND_CAP;
    for (int j = threadIdx.x; j < C; j += 256) sk[j] = cand[j];
    __syncthreads();
    for (int i = blockIdx.x * 256 + threadIdx.x; i < C; i += gridDim.x * 256) {
        u64 ki = sk[i];
        int rank = 0;
        for (int j = 0; j < C; ++j) rank += (sk[j] > ki);
        if (rank < TOPK_N) {
            unsigned key = (unsigned)(ki >> 32);
            int anchor = (int)(~(unsigned)ki);
            tkscore[rank] = __uint_as_float(key);
            int lab = labels[anchor];
            tklabel[rank] = lab;
            float4 b = box[anchor];
            boxes_k[rank] = b;
            float off = (float)lab * 4096.0f;
            float4 ob = make_float4(b.x + off, b.y + off, b.z + off, b.w + off);
            obx[rank] = ob;
            areas[rank] = fmaxf(ob.z - ob.x, 0.0f) * fmaxf(ob.w - ob.y, 0.0f);
        }
    }
}

// K5: 1000x1000 suppression bitmask: bit j of row i set iff j>i and IoU>0.5.
__global__ void k5_iou(const float4* __restrict__ obx,
                       const float* __restrict__ areas,
                       u64* __restrict__ mask) {
    int i = blockIdx.x;
    int lane = threadIdx.x;           // 64
    float4 bi = obx[i];
    float ai = areas[i];
    for (int w = 0; w < 16; ++w) {
        int c = w * 64 + lane;
        bool bit = false;
        if (c < TOPK_N && c > i) {
            float4 bc = obx[c];
            float xx1 = fmaxf(bi.x, bc.x), yy1 = fmaxf(bi.y, bc.y);
            float xx2 = fminf(bi.z, bc.z), yy2 = fminf(bi.w, bc.w);
            float inter = fmaxf(xx2 - xx1, 0.0f) * fmaxf(yy2 - yy1, 0.0f);
            float iou = inter / (ai + areas[c] - inter + 1e-9f);
            bit = iou > 0.5f;
        }
        u64 bal = __ballot(bit);
        if (lane == 0) mask[(size_t)i * 16 + w] = bal;
    }
}

// K6: greedy NMS with the whole mask LDS-resident. 64 boxes per batch,
// suppression state distributed over 64 lanes (4 row-slots x 16 words).
__global__ void k6_nms(const float* __restrict__ tkscore,
                       const u64* __restrict__ mask,
                       float* __restrict__ keepf) {
    __shared__ u64 smask[TOPK_N * 16];   // 128 KB
    int t = threadIdx.x;                 // 256
    for (int j = t; j < TOPK_N * 16; j += 256) smask[j] = mask[j];
    __syncthreads();
    if (t >= 64) return;                 // wave 0 only beyond this point
    int lane = t;
    int g = lane >> 4, w = lane & 15;
    u64 part = 0;                        // partial removed: word w, row-slot g
    for (int b = 0; b < 16; ++b) {
        int i0 = b * 64;
        float sc = tkscore[i0 + lane];
        // canonical removed word b, broadcast to all lanes
        u64 canon = part;
        canon |= shflxor64(canon, 16);
        canon |= shflxor64(canon, 32);
        u64 rw = shfl64(canon, b);
        u64 conf = __ballot(sc > 0.001f);
        u64 alive = conf & ~rw;
        // intra-batch greedy resolution (alive is wave-uniform)
        #pragma unroll
        for (int k0 = 0; k0 < 64; k0 += 8) {
            u64 d[8];
            #pragma unroll
            for (int q = 0; q < 8; ++q) d[q] = smask[(size_t)(i0 + k0 + q) * 16 + b];
            #pragma unroll
            for (int q = 0; q < 8; ++q)
                if ((alive >> (k0 + q)) & 1) alive &= ~d[q];
        }
        keepf[i0 + lane] = (float)((alive >> lane) & 1);
        // accumulate suppression rows of kept boxes, 4 rows per iteration
        u64 a = alive;
        while (a) {
            int idx[4]; int n = 0;
            #pragma unroll
            for (int q = 0; q < 4; ++q) {
                idx[q] = 0;
                if (a) { idx[q] = __ffsll((long long)a) - 1; a &= a - 1; ++n; }
            }
            if (g < n) part |= smask[(size_t)(i0 + idx[g]) * 16 + w];
        }
    }
}

// K7: final outputs: [1000x5 out5][1000 labels][1000 keep], all float32.
__global__ void k7_write(const float* __restrict__ tkscore,
                         const int* __restrict__ tklabel,
                         const float4* __restrict__ boxes_k,
                         const float* __restrict__ keepf,
                         float* __restrict__ out) {
    int j = blockIdx.x * blockDim.x + threadIdx.x;
    if (j >= TOPK_N) return;
    float k = keepf[j];
    float4 b = boxes_k[j];
    out[j * 5 + 0] = tkscore[j] * k;
    out[j * 5 + 1] = b.x * k;
    out[j * 5 + 2] = b.y * k;
    out[j * 5 + 3] = b.z * k;
    out[j * 5 + 4] = b.w * k;
    out[5 * TOPK_N + j] = (float)tklabel[j];
    out[6 * TOPK_N + j] = k;
}

extern "C" void kernel_launch(void* const* d_in, const int* in_sizes, int n_in,
                              void* d_out, int out_size, void* d_ws, size_t ws_size,
                              hipStream_t stream) {
    const float* obj = (const float*)d_in[0];
    const float* cls = (const float*)d_in[1];
    const float* box = (const float*)d_in[2];
    float* out = (float*)d_out;
    char* ws = (char*)d_ws;
    int M = in_sizes[0];   // 300000

    float*    scores  = (float*)(ws + WS_SCORES);
    int*      labels  = (int*)(ws + WS_LABELS);
    int*      meta    = (int*)(ws + WS_META);
    u64*      cand    = (u64*)(ws + WS_CAND);
    float*    tkscore = (float*)(ws + WS_TKSCORE);
    int*      tklabel = (int*)(ws + WS_TKLABEL);
    float4*   boxes_k = (float4*)(ws + WS_BOXES);
    float4*   obx     = (float4*)(ws + WS_OBX);
    float*    areas   = (float*)(ws + WS_AREAS);
    u64*      mask    = (u64*)(ws + WS_MASK);
    float*    keepf   = (float*)(ws + WS_KEEPF);
    unsigned* hist    = (unsigned*)(ws + WS_HIST);

    // histogram replica count: largest pow2 that fits, capped at 32
    size_t avail = (ws_size > (size_t)WS_HIST) ? ws_size - WS_HIST : REPLICA_BYTES;
    int R = (int)(avail / REPLICA_BYTES);
    if (R < 1) R = 1;
    if (R > 32) R = 32;
    int Rp = 1;
    while (Rp * 2 <= R) Rp *= 2;

    hipMemsetAsync(ws + WS_META, 0, 64, stream);
    hipMemsetAsync(ws + WS_HIST, 0, (size_t)Rp * REPLICA_BYTES, stream);

    k1_scores<<<(M + 15) / 16, 256, 0, stream>>>(obj, cls, scores, labels, hist, Rp - 1, M);
    k_hreduce<<<HIST_BINS / 256, 256, 0, stream>>>(hist, Rp);
    k2_scan<<<1, 1024, 0, stream>>>(hist, meta);
    k3_compact<<<(M + 255) / 256, 256, 0, stream>>>(scores, meta, cand, meta + 2, M);
    k4_rank<<<32, 256, 0, stream>>>(cand, meta, labels, (const float4*)box,
                                    tkscore, tklabel, boxes_k, obx, areas);
    k5_iou<<<TOPK_N, 64, 0, stream>>>(obx, areas, mask);
    k6_nms<<<1, 256, 0, stream>>>(tkscore, mask, keepf);
    k7_write<<<(TOPK_N + 63) / 64, 64, 0, stream>>>(tkscore, tklabel, boxes_k, keepf, out);
}

// Round 3
// 237.170 us; speedup vs baseline: 3.5238x; 1.3418x over previous
//
#include <hip/hip_runtime.h>
#include <hip/hip_bf16.h>
#include <math.h>

#define NCLS 80
#define TOPK_N 1000
#define CAND_CAP 4096
#define HIST_BINS 131072        // 17-bit bins of float score bits
#define REPLICA_BYTES (HIST_BINS * 4)

// ---- workspace layout (bytes), M = 300000 ----
#define WS_SCORES   0           // 300000 f32
#define WS_LABELS   1200000     // 300000 i32
#define WS_CAND     2400000     // 4096 u64
#define WS_TKSCORE  2432768     // 1000 f32
#define WS_TKLABEL  2436768     // 1000 i32
#define WS_BOXES    2440768     // 1000 float4 (original boxes)
#define WS_OBX      2456768     // 1000 float4 (class-offset boxes)
#define WS_AREAS    2472768     // 1000 f32
#define WS_MASK     2476768     // 1000 * 16 u64 TRANSPOSED sup mask
#define WS_META     2604768     // [0]=bin B, [1]=count_above, [2]=cand counter
#define WS_HIST     2604832     // R * 131072 u32 (replicated histogram)
// fixed + 1 replica = 3,129,120 B

typedef unsigned long long u64;

__device__ __forceinline__ float sigmoidf_(float x) {
    return 1.0f / (1.0f + expf(-x));
}

// K1: 16 lanes per anchor (4 anchors/wave). float4 loads, shfl_xor reduce,
// replicated-histogram atomic (replica = blockIdx & (R-1)).
__global__ void k1_scores(const float* __restrict__ obj,
                          const float* __restrict__ cls,
                          float* __restrict__ scores,
                          int* __restrict__ labels,
                          unsigned* __restrict__ hist, int Rm1, int M) {
    int wave = (blockIdx.x * 256 + threadIdx.x) >> 6;
    int lane = threadIdx.x & 63;
    int g = lane >> 4, l = lane & 15;
    int anchor = wave * 4 + g;
    if (anchor >= M) return;
    const float4* row = (const float4*)(cls + (size_t)anchor * NCLS);
    float4 v4 = row[l];
    float bv = v4.x; int bc = l * 4;
    if (v4.y > bv) { bv = v4.y; bc = l * 4 + 1; }
    if (v4.z > bv) { bv = v4.z; bc = l * 4 + 2; }
    if (v4.w > bv) { bv = v4.w; bc = l * 4 + 3; }
    if (l < 4) {                         // classes 64..79
        float4 w4 = row[16 + l];
        int cb = 64 + l * 4;
        if (w4.x > bv) { bv = w4.x; bc = cb; }
        if (w4.y > bv) { bv = w4.y; bc = cb + 1; }
        if (w4.z > bv) { bv = w4.z; bc = cb + 2; }
        if (w4.w > bv) { bv = w4.w; bc = cb + 3; }
    }
    #pragma unroll
    for (int m = 8; m >= 1; m >>= 1) {   // reduce within 16-lane group
        float ov = __shfl_xor(bv, m);
        int oc = __shfl_xor(bc, m);
        if (ov > bv || (ov == bv && oc < bc)) { bv = ov; bc = oc; }
    }
    if (l == 0) {
        float so = sigmoidf_(obj[anchor]);
        float score = sqrtf(so * sigmoidf_(bv));
        scores[anchor] = score;
        labels[anchor] = bc;
        unsigned key = __float_as_uint(score);
        int rep = blockIdx.x & Rm1;
        atomicAdd(&hist[(size_t)rep * HIST_BINS + (key >> 15)], 1u);
    }
}

// K1b: fold R replicas into replica 0.
__global__ void k_hreduce(unsigned* __restrict__ hist, int R) {
    int b = blockIdx.x * 256 + threadIdx.x;
    unsigned s = hist[b];
    for (int r = 1; r < R; ++r) s += hist[(size_t)r * HIST_BINS + b];
    hist[b] = s;
}

// K2: find threshold bin B (descending) where cumulative count reaches TOPK_N.
__global__ void k2_scan(const unsigned* __restrict__ hist, int* __restrict__ meta) {
    int t = threadIdx.x;              // 1024
    int lane = t & 63, w = t >> 6;    // 16 waves
    int base = HIST_BINS - 1 - t * 128;
    unsigned s = 0;
    for (int k = 0; k < 128; ++k) s += hist[base - k];
    unsigned inc = s;
    for (int d = 1; d < 64; d <<= 1) {
        unsigned pv = __shfl_up(inc, d);
        if (lane >= d) inc += pv;
    }
    __shared__ unsigned wsum[16], woff[16];
    if (lane == 63) wsum[w] = inc;
    __syncthreads();
    if (t == 0) {
        unsigned cum = 0;
        for (int i = 0; i < 16; ++i) { woff[i] = cum; cum += wsum[i]; }
    }
    __syncthreads();
    unsigned excl = woff[w] + inc - s;
    if (excl < TOPK_N && excl + s >= TOPK_N) {   // exactly one thread
        unsigned cum = excl; int b = base;
        for (int k = 0; k < 128; ++k) {
            unsigned h = hist[b];
            if (cum + h >= TOPK_N) { meta[0] = b; meta[1] = (int)cum; break; }
            cum += h; --b;
        }
    }
}

// K3: compact candidates with key_high >= B into composite keys.
__global__ void k3_compact(const float* __restrict__ scores,
                           const int* __restrict__ meta,
                           u64* __restrict__ cand,
                           int* __restrict__ counter, int M) {
    int i = blockIdx.x * blockDim.x + threadIdx.x;
    if (i >= M) return;
    unsigned key = __float_as_uint(scores[i]);
    if ((int)(key >> 15) >= meta[0]) {
        int pos = atomicAdd(counter, 1);
        if (pos < CAND_CAP) {
            cand[pos] = ((u64)key << 32) | (unsigned)(~i);
        }
    }
}

// K4: rank-by-counting. rank(i) = #{j: key_j > key_i}; scatter rank < 1000.
__global__ void k4_rank(const u64* __restrict__ cand,
                        const int* __restrict__ meta,
                        const int* __restrict__ labels,
                        const float4* __restrict__ box,
                        float* __restrict__ tkscore,
                        int* __restrict__ tklabel,
                        float4* __restrict__ boxes_k,
                        float4* __restrict__ obx,
                        float* __restrict__ areas) {
    __shared__ u64 sk[CAND_CAP];
    int C = meta[2];
    if (C > CAND_CAP) C = CAND_CAP;
    for (int j = threadIdx.x; j < C; j += 256) sk[j] = cand[j];
    __syncthreads();
    for (int i = blockIdx.x * 256 + threadIdx.x; i < C; i += gridDim.x * 256) {
        u64 ki = sk[i];
        int rank = 0;
        for (int j = 0; j < C; ++j) rank += (sk[j] > ki);
        if (rank < TOPK_N) {
            unsigned key = (unsigned)(ki >> 32);
            int anchor = (int)(~(unsigned)ki);
            tkscore[rank] = __uint_as_float(key);
            int lab = labels[anchor];
            tklabel[rank] = lab;
            float4 b = box[anchor];
            boxes_k[rank] = b;
            float off = (float)lab * 4096.0f;
            float4 ob = make_float4(b.x + off, b.y + off, b.z + off, b.w + off);
            obx[rank] = ob;
            areas[rank] = fmaxf(ob.z - ob.x, 0.0f) * fmaxf(ob.w - ob.y, 0.0f);
        }
    }
}

// K5: TRANSPOSED suppression mask: bit j of row i set iff j<i and IoU>0.5.
__global__ void k5_iou(const float4* __restrict__ obx,
                       const float* __restrict__ areas,
                       u64* __restrict__ mask) {
    int i = blockIdx.x;
    int lane = threadIdx.x;           // 64
    float4 bi = obx[i];
    float ai = areas[i];
    for (int w = 0; w < 16; ++w) {
        int c = w * 64 + lane;
        bool bit = false;
        if (c < i) {                  // only lower-indexed suppressors
            float4 bc = obx[c];
            float xx1 = fmaxf(bi.x, bc.x), yy1 = fmaxf(bi.y, bc.y);
            float xx2 = fminf(bi.z, bc.z), yy2 = fminf(bi.w, bc.w);
            float inter = fmaxf(xx2 - xx1, 0.0f) * fmaxf(yy2 - yy1, 0.0f);
            float iou = inter / (ai + areas[c] - inter + 1e-9f);
            bit = iou > 0.5f;
        }
        u64 bal = __ballot(bit);
        if (lane == 0) mask[(size_t)i * 16 + w] = bal;
    }
}

// K6: parallel exact greedy NMS by fixed-point rounds + fused output write.
// Thread i owns box i. sup[] = suppressors (j<i, iou>0.5) in registers.
// A box decides once all its suppressors are decided; kept iff no kept
// suppressor. Lowest undecided index is always decidable => terminates.
__global__ void __launch_bounds__(1024)
k6_nms(const float* __restrict__ tkscore,
       const u64* __restrict__ mask,
       const int* __restrict__ tklabel,
       const float4* __restrict__ boxes_k,
       float* __restrict__ out) {
    __shared__ u64 kept_s[16], dec_s[16];
    __shared__ int ndec;
    int t = threadIdx.x;              // 1024
    bool active = t < TOPK_N;
    if (t < 16) { kept_s[t] = 0ULL; dec_s[t] = 0ULL; }
    if (t == 0) ndec = 0;
    u64 sup[16];
    if (active) {
        #pragma unroll
        for (int w = 0; w < 16; ++w) sup[w] = mask[(size_t)t * 16 + w];
    }
    float sc = active ? tkscore[t] : 0.0f;
    bool conf = sc > 0.001f;
    bool mydec = false, mykept = false;
    __syncthreads();
    for (int round = 0; round < TOPK_N; ++round) {
        bool newdec = false;
        if (active && !mydec) {
            if (!conf) {
                newdec = true; mykept = false;
            } else {
                u64 pend = 0;
                #pragma unroll
                for (int w = 0; w < 16; ++w) pend |= sup[w] & ~dec_s[w];
                if (pend == 0ULL) {
                    u64 kk = 0;
                    #pragma unroll
                    for (int w = 0; w < 16; ++w) kk |= sup[w] & kept_s[w];
                    newdec = true; mykept = (kk == 0ULL);
                }
            }
        }
        __syncthreads();   // all reads of dec_s/kept_s done
        if (newdec) {
            mydec = true;
            atomicOr(&dec_s[t >> 6], 1ULL << (t & 63));
            if (mykept) atomicOr(&kept_s[t >> 6], 1ULL << (t & 63));
            atomicAdd(&ndec, 1);
        }
        __syncthreads();   // updates visible
        if (ndec >= TOPK_N) break;
    }
    if (active) {
        float k = mykept ? 1.0f : 0.0f;
        float4 b = boxes_k[t];
        out[t * 5 + 0] = sc * k;
        out[t * 5 + 1] = b.x * k;
        out[t * 5 + 2] = b.y * k;
        out[t * 5 + 3] = b.z * k;
        out[t * 5 + 4] = b.w * k;
        out[5 * TOPK_N + t] = (float)tklabel[t];
        out[6 * TOPK_N + t] = k;
    }
}

extern "C" void kernel_launch(void* const* d_in, const int* in_sizes, int n_in,
                              void* d_out, int out_size, void* d_ws, size_t ws_size,
                              hipStream_t stream) {
    const float* obj = (const float*)d_in[0];
    const float* cls = (const float*)d_in[1];
    const float* box = (const float*)d_in[2];
    float* out = (float*)d_out;
    char* ws = (char*)d_ws;
    int M = in_sizes[0];   // 300000

    float*    scores  = (float*)(ws + WS_SCORES);
    int*      labels  = (int*)(ws + WS_LABELS);
    u64*      cand    = (u64*)(ws + WS_CAND);
    float*    tkscore = (float*)(ws + WS_TKSCORE);
    int*      tklabel = (int*)(ws + WS_TKLABEL);
    float4*   boxes_k = (float4*)(ws + WS_BOXES);
    float4*   obx     = (float4*)(ws + WS_OBX);
    float*    areas   = (float*)(ws + WS_AREAS);
    u64*      mask    = (u64*)(ws + WS_MASK);
    int*      meta    = (int*)(ws + WS_META);
    unsigned* hist    = (unsigned*)(ws + WS_HIST);

    // histogram replica count: largest pow2 that fits, capped at 32
    size_t avail = (ws_size > (size_t)WS_HIST) ? ws_size - WS_HIST : REPLICA_BYTES;
    int R = (int)(avail / REPLICA_BYTES);
    if (R < 1) R = 1;
    if (R > 32) R = 32;
    int Rp = 1;
    while (Rp * 2 <= R) Rp *= 2;

    // single memset covers META (64B) + all histogram replicas
    hipMemsetAsync(ws + WS_META, 0, 64 + (size_t)Rp * REPLICA_BYTES, stream);

    k1_scores<<<(M + 15) / 16, 256, 0, stream>>>(obj, cls, scores, labels, hist, Rp - 1, M);
    k_hreduce<<<HIST_BINS / 256, 256, 0, stream>>>(hist, Rp);
    k2_scan<<<1, 1024, 0, stream>>>(hist, meta);
    k3_compact<<<(M + 255) / 256, 256, 0, stream>>>(scores, meta, cand, meta + 2, M);
    k4_rank<<<32, 256, 0, stream>>>(cand, meta, labels, (const float4*)box,
                                    tkscore, tklabel, boxes_k, obx, areas);
    k5_iou<<<TOPK_N, 64, 0, stream>>>(obx, areas, mask);
    k6_nms<<<1, 1024, 0, stream>>>(tkscore, mask, tklabel, boxes_k, out);
}